// Round 1
// baseline (485.983 us; speedup 1.0000x reference)
//
#include <hip/hip_runtime.h>
#include <stdint.h>

#define TB 512
#define SCALE 0.17677669529663687f  // 1/sqrt(32)

__device__ __forceinline__ float bf2f(uint16_t u) {
    union { uint32_t i; float f; } v; v.i = ((uint32_t)u) << 16; return v.f;
}
__device__ __forceinline__ uint16_t f2bf(float f) {
    union { float f; uint32_t i; } v; v.f = f;
    uint32_t r = v.i + 0x7fffu + ((v.i >> 16) & 1u);
    return (uint16_t)(r >> 16);
}
__device__ __forceinline__ void unpack8(uint4 p, float* o) {
    o[0] = bf2f((uint16_t)(p.x & 0xffffu)); o[1] = bf2f((uint16_t)(p.x >> 16));
    o[2] = bf2f((uint16_t)(p.y & 0xffffu)); o[3] = bf2f((uint16_t)(p.y >> 16));
    o[4] = bf2f((uint16_t)(p.z & 0xffffu)); o[5] = bf2f((uint16_t)(p.z >> 16));
    o[6] = bf2f((uint16_t)(p.w & 0xffffu)); o[7] = bf2f((uint16_t)(p.w >> 16));
}

// ---------------- K1: light positional embedding -> le[b][i][j][s] ----------------
__global__ void light_emb_kernel(const float* __restrict__ light,
                                 const float* __restrict__ lw1, const float* __restrict__ lb1,
                                 const float* __restrict__ lw2, const float* __restrict__ lb2,
                                 const float* __restrict__ lw3, const float* __restrict__ lb3,
                                 float* __restrict__ le) {
    int e = blockIdx.x * 256 + threadIdx.x;
    if (e >= 4 * 33 * 33) return;
    int j = e % 33;
    int i = (e / 33) % 33;
    int b = e / (33 * 33);
    float d[3];
    #pragma unroll
    for (int c = 0; c < 3; ++c) {
        float a  = (i < 32) ? light[(b * 3 + c) * 32 + i] : -1.0f;
        float bb = (j < 32) ? light[(b * 3 + c) * 32 + j] : -1.0f;
        d[c] = a - bb;
    }
    float h1[8];
    #pragma unroll
    for (int o = 0; o < 8; ++o) {
        float s = lb1[o];
        #pragma unroll
        for (int c = 0; c < 3; ++c) s += lw1[o * 3 + c] * d[c];
        h1[o] = (s >= 0.f) ? s : 0.1f * s;
    }
    float h2[16];
    #pragma unroll
    for (int o = 0; o < 16; ++o) {
        float s = lb2[o];
        #pragma unroll
        for (int c = 0; c < 8; ++c) s += lw2[o * 8 + c] * h1[c];
        h2[o] = (s >= 0.f) ? s : 0.1f * s;
    }
    float* dst = le + (size_t)e * 32;
    #pragma unroll
    for (int o = 0; o < 32; ++o) {
        float s = lb3[o];
        #pragma unroll
        for (int c = 0; c < 16; ++c) s += lw3[o * 16 + c] * h2[c];
        dst[o] = s;
    }
}

// ---------------- K2: fused attention over one (b, h, 8-wide w tile) ----------------
__launch_bounds__(TB, 1)
__global__ void fused_attn_kernel(const float* __restrict__ x,
                                  const float* __restrict__ wk, const float* __restrict__ bk,
                                  const float* __restrict__ wq, const float* __restrict__ bq,
                                  const float* __restrict__ wv, const float* __restrict__ bv,
                                  const float* __restrict__ wo, const float* __restrict__ bo,
                                  const float* __restrict__ le,
                                  float* __restrict__ out) {
    // regA: xs [(c*33+m)*8 + w]  (16896 f)   then   sc [(px*32+j')*33+i] (8448 f) | ob at +8448 (10240 f)
    __shared__ __align__(16) float    regA[18688];
    __shared__ __align__(16) uint16_t kq[64 * 33 * 8];   // bf16 [q][m][px], q: 0..31 = k rows, 32..63 = q rows
    __shared__ __align__(16) uint16_t v2[8 * 32 * 33];   // bf16 [px][s][m]
    __shared__ __align__(16) float    wbuf[96 * 65];     // fused W [q][c], stride 65 (bank spread)
    __shared__ float bias[96];
    __shared__ float wol[61 * 33];                       // wo [oc][s], stride 33
    __shared__ float bol[61];

    const int t   = threadIdx.x;
    const int blk = blockIdx.x;
    const int b   = blk >> 9;
    const int h   = (blk >> 3) & 63;
    const int w0  = (blk & 7) << 3;

    // ---- phase 0: stage weights + load xs (m = 1..32) ----
    for (int e = t; e < 96 * 64; e += TB) {
        int q = e >> 6, c = e & 63;
        float v = (q < 32) ? wk[e] : (q < 64) ? wq[e - 2048] : wv[e - 4096];
        wbuf[q * 65 + c] = v;
    }
    if (t < 96) bias[t] = (t < 32) ? bk[t] : (t < 64) ? bq[t - 32] : bv[t - 64];
    for (int e = t; e < 61 * 32; e += TB) wol[(e >> 5) * 33 + (e & 31)] = wo[e];
    if (t < 61) bol[t] = bo[t];
    {
        const int w = t & 7, n = (t >> 3) & 31, c0 = t >> 8;
        for (int c = c0; c < 64; c += 2) {
            float v = x[((((size_t)(b * 64 + c)) * 32 + n) * 64 + h) * 64 + w0 + w];
            regA[(c * 33 + (n + 1)) * 8 + w] = v;
        }
    }
    __syncthreads();

    // ---- phase A2: extra token (m = 0) = max over m = 1..32 ----
    {
        const int c = t >> 3, w = t & 7;
        float mx = regA[(c * 33 + 1) * 8 + w];
        for (int m = 2; m <= 32; ++m) mx = fmaxf(mx, regA[(c * 33 + m) * 8 + w]);
        regA[(c * 33) * 8 + w] = mx;
    }
    __syncthreads();

    // ---- phase B1: k,q rows (q = 0..63) for m = 0..31 ----
    {
        const int m = t & 31, qg = t >> 5;  // q = qg*4 .. qg*4+3
        float acc[4][8];
        #pragma unroll
        for (int qq = 0; qq < 4; ++qq) {
            float bb = bias[qg * 4 + qq];
            #pragma unroll
            for (int w = 0; w < 8; ++w) acc[qq][w] = bb;
        }
        for (int c = 0; c < 64; ++c) {
            float4 x0 = *(const float4*)&regA[(c * 33 + m) * 8];
            float4 x1 = *(const float4*)&regA[(c * 33 + m) * 8 + 4];
            #pragma unroll
            for (int qq = 0; qq < 4; ++qq) {
                float wv_ = wbuf[(qg * 4 + qq) * 65 + c];
                acc[qq][0] += wv_ * x0.x; acc[qq][1] += wv_ * x0.y;
                acc[qq][2] += wv_ * x0.z; acc[qq][3] += wv_ * x0.w;
                acc[qq][4] += wv_ * x1.x; acc[qq][5] += wv_ * x1.y;
                acc[qq][6] += wv_ * x1.z; acc[qq][7] += wv_ * x1.w;
            }
        }
        #pragma unroll
        for (int qq = 0; qq < 4; ++qq) {
            int q = qg * 4 + qq;
            uint4 pk;
            pk.x = (uint32_t)f2bf(acc[qq][0]) | ((uint32_t)f2bf(acc[qq][1]) << 16);
            pk.y = (uint32_t)f2bf(acc[qq][2]) | ((uint32_t)f2bf(acc[qq][3]) << 16);
            pk.z = (uint32_t)f2bf(acc[qq][4]) | ((uint32_t)f2bf(acc[qq][5]) << 16);
            pk.w = (uint32_t)f2bf(acc[qq][6]) | ((uint32_t)f2bf(acc[qq][7]) << 16);
            *(uint4*)&kq[(q * 33 + m) * 8] = pk;
        }
    }
    // ---- phase B2: v rows (s = 0..31) for m = 0..31 ----
    {
        const int m = t & 31, sg = t >> 5;  // s = sg*2, sg*2+1
        float acc[2][8];
        #pragma unroll
        for (int sq = 0; sq < 2; ++sq) {
            float bb = bias[64 + sg * 2 + sq];
            #pragma unroll
            for (int w = 0; w < 8; ++w) acc[sq][w] = bb;
        }
        for (int c = 0; c < 64; ++c) {
            float4 x0 = *(const float4*)&regA[(c * 33 + m) * 8];
            float4 x1 = *(const float4*)&regA[(c * 33 + m) * 8 + 4];
            #pragma unroll
            for (int sq = 0; sq < 2; ++sq) {
                float wv_ = wbuf[(64 + sg * 2 + sq) * 65 + c];
                acc[sq][0] += wv_ * x0.x; acc[sq][1] += wv_ * x0.y;
                acc[sq][2] += wv_ * x0.z; acc[sq][3] += wv_ * x0.w;
                acc[sq][4] += wv_ * x1.x; acc[sq][5] += wv_ * x1.y;
                acc[sq][6] += wv_ * x1.z; acc[sq][7] += wv_ * x1.w;
            }
        }
        #pragma unroll
        for (int sq = 0; sq < 2; ++sq) {
            int s = sg * 2 + sq;
            #pragma unroll
            for (int w = 0; w < 8; ++w) v2[(w * 32 + s) * 33 + m] = f2bf(acc[sq][w]);
        }
    }
    // ---- phase B3: m = 32 ----
    {
        const int w = t & 7, qi = t >> 3;
        #pragma unroll
        for (int rep = 0; rep < 2; ++rep) {
            int q = qi + rep * 64;
            if (q < 96) {
                float a = bias[q];
                for (int c = 0; c < 64; ++c)
                    a += wbuf[q * 65 + c] * regA[(c * 33 + 32) * 8 + w];
                if (q < 64) kq[(q * 33 + 32) * 8 + w] = f2bf(a);
                else        v2[(w * 32 + (q - 64)) * 33 + 32] = f2bf(a);
            }
        }
    }
    __syncthreads();

    float* sc = regA;            // [px][j'][i], j' = j-1 in 0..31, i in 0..32
    float* ob = regA + 8448;     // [g'][px][40] with s-chunk XOR swizzle

    // ---- phase C1: raw scores (only query cols j = 1..32 are ever used) ----
    for (int e = t; e < 544; e += TB) {
        int jp = e & 31, ig = e >> 5;
        int j = jp + 1;
        int i0 = ig * 2;
        bool has1 = (i0 + 1 < 33);
        float a0[8], a1[8];
        #pragma unroll
        for (int p = 0; p < 8; ++p) { a0[p] = 0.f; a1[p] = 0.f; }
        for (int s = 0; s < 32; ++s) {
            float kt0[8], kt1[8], qt[8];
            unpack8(*(const uint4*)&kq[(s * 33 + i0) * 8], kt0);
            unpack8(*(const uint4*)&kq[((32 + s) * 33 + j) * 8], qt);
            if (has1) unpack8(*(const uint4*)&kq[(s * 33 + i0 + 1) * 8], kt1);
            #pragma unroll
            for (int p = 0; p < 8; ++p) {
                a0[p] += kt0[p] * qt[p];
                if (has1) a1[p] += kt1[p] * qt[p];
            }
        }
        #pragma unroll
        for (int p = 0; p < 8; ++p) {
            sc[(p * 32 + jp) * 33 + i0] = a0[p] * SCALE;
            if (has1) sc[(p * 32 + jp) * 33 + i0 + 1] = a1[p] * SCALE;
        }
    }
    __syncthreads();

    // ---- phase C2a: softmax over key index i, per (px, j) column ----
    if (t < 256) {
        int px = t >> 5, jp = t & 31;
        float* col = &sc[(px * 32 + jp) * 33];
        float mx = col[0];
        for (int i = 1; i < 33; ++i) mx = fmaxf(mx, col[i]);
        float sum = 0.f;
        for (int i = 0; i < 33; ++i) { float e_ = __expf(col[i] - mx); sum += e_; col[i] = e_; }
        float r = 1.0f / sum;
        for (int i = 0; i < 33; ++i) col[i] *= r;
    }
    __syncthreads();

    // ---- phase C2b: a[i][j] += sum_s qt[s][i] * le[b][s][i][j] ----
    for (int e = t; e < 1056; e += TB) {
        int i = e % 33, jp = e / 33;
        int j = jp + 1;
        const float* lep = le + ((((size_t)b * 33 + i) * 33 + j) << 5);
        float accb[8];
        #pragma unroll
        for (int p = 0; p < 8; ++p) accb[p] = 0.f;
        #pragma unroll
        for (int s4 = 0; s4 < 8; ++s4) {
            float4 lv = *(const float4*)&lep[s4 * 4];
            const float ls[4] = { lv.x, lv.y, lv.z, lv.w };
            #pragma unroll
            for (int k = 0; k < 4; ++k) {
                int s = s4 * 4 + k;
                float qt[8];
                unpack8(*(const uint4*)&kq[((32 + s) * 33 + i) * 8], qt);
                #pragma unroll
                for (int p = 0; p < 8; ++p) accb[p] += qt[p] * ls[k];
            }
        }
        #pragma unroll
        for (int p = 0; p < 8; ++p) sc[(p * 32 + jp) * 33 + i] += accb[p];
    }
    __syncthreads();

    // ---- phase C3: o[s][g] = sum_m v[s][m] * a[m][g]  (wave <-> pixel) ----
    {
        int px = t >> 6, l = t & 63;
        int s0 = (l >> 3) << 2, g0 = (l & 7) << 2;
        float4 accv[4];
        #pragma unroll
        for (int kg = 0; kg < 4; ++kg) accv[kg] = make_float4(0.f, 0.f, 0.f, 0.f);
        for (int m = 0; m < 33; ++m) {
            float vv[4];
            #pragma unroll
            for (int ks = 0; ks < 4; ++ks) vv[ks] = bf2f(v2[(px * 32 + s0 + ks) * 33 + m]);
            #pragma unroll
            for (int kg = 0; kg < 4; ++kg) {
                float av = sc[(px * 32 + g0 + kg) * 33 + m];
                accv[kg].x += vv[0] * av; accv[kg].y += vv[1] * av;
                accv[kg].z += vv[2] * av; accv[kg].w += vv[3] * av;
            }
        }
        #pragma unroll
        for (int kg = 0; kg < 4; ++kg) {
            int g = g0 + kg;
            *(float4*)&ob[(g * 8 + px) * 40 + (s0 ^ ((g & 7) << 2))] = accv[kg];
        }
    }
    __syncthreads();

    // ---- phase D: ao = wo @ o + bo, residual add, write out ----
    {
        const int w = t & 7, c = t >> 3;
        const size_t xbase = (((size_t)(b * 64 + c)) * 32) * 4096 + (size_t)h * 64 + w0 + w;
        if (c < 3) {
            for (int n = 0; n < 32; ++n)
                out[xbase + (size_t)n * 4096] = x[xbase + (size_t)n * 4096];
        } else {
            int oc = c - 3;
            float wr[32];
            #pragma unroll
            for (int s = 0; s < 32; ++s) wr[s] = wol[oc * 33 + s];
            float bb = bol[oc];
            for (int n = 0; n < 32; ++n) {
                float acc = bb;
                #pragma unroll
                for (int cs = 0; cs < 8; ++cs) {
                    float4 ov = *(const float4*)&ob[(n * 8 + w) * 40 + ((cs << 2) ^ ((n & 7) << 2))];
                    acc += ov.x * wr[cs * 4] + ov.y * wr[cs * 4 + 1] +
                           ov.z * wr[cs * 4 + 2] + ov.w * wr[cs * 4 + 3];
                }
                out[xbase + (size_t)n * 4096] = x[xbase + (size_t)n * 4096] + acc;
            }
        }
    }
}

extern "C" void kernel_launch(void* const* d_in, const int* in_sizes, int n_in,
                              void* d_out, int out_size, void* d_ws, size_t ws_size,
                              hipStream_t stream) {
    const float* x     = (const float*)d_in[0];
    const float* light = (const float*)d_in[1];
    const float* wk  = (const float*)d_in[2];
    const float* bk  = (const float*)d_in[3];
    const float* wq  = (const float*)d_in[4];
    const float* bq  = (const float*)d_in[5];
    const float* wv  = (const float*)d_in[6];
    const float* bv  = (const float*)d_in[7];
    const float* wo  = (const float*)d_in[8];
    const float* bo  = (const float*)d_in[9];
    const float* lw1 = (const float*)d_in[10];
    const float* lb1 = (const float*)d_in[11];
    const float* lw2 = (const float*)d_in[12];
    const float* lb2 = (const float*)d_in[13];
    const float* lw3 = (const float*)d_in[14];
    const float* lb3 = (const float*)d_in[15];
    float* out = (float*)d_out;
    float* le  = (float*)d_ws;  // 4*33*33*32 floats = 557 KB

    light_emb_kernel<<<dim3((4 * 33 * 33 + 255) / 256), dim3(256), 0, stream>>>(
        light, lw1, lb1, lw2, lb2, lw3, lb3, le);
    fused_attn_kernel<<<dim3(2048), dim3(TB), 0, stream>>>(
        x, wk, bk, wq, bq, wv, bv, wo, bo, le, out);
}

// Round 2
// 216.516 us; speedup vs baseline: 2.2446x; 2.2446x over previous
//
#include <hip/hip_runtime.h>
#include <stdint.h>

#define TB 512
#define SCALE 0.17677669529663687f  // 1/sqrt(32)

typedef __attribute__((ext_vector_type(8))) short short8;
typedef __attribute__((ext_vector_type(4))) float f32x4;
#define MFMA(a, b, c) __builtin_amdgcn_mfma_f32_16x16x32_bf16(a, b, c, 0, 0, 0)

__device__ __forceinline__ float bf2f(uint16_t u) {
    union { uint32_t i; float f; } v; v.i = ((uint32_t)u) << 16; return v.f;
}
__device__ __forceinline__ uint16_t f2bf(float f) {
    union { float f; uint32_t i; } v; v.f = f;
    uint32_t r = v.i + 0x7fffu + ((v.i >> 16) & 1u);
    return (uint16_t)(r >> 16);
}

// ---------------- K1: light positional embedding -> le[b][i][j][s] (f32) ----------------
__global__ void light_emb_kernel(const float* __restrict__ light,
                                 const float* __restrict__ lw1, const float* __restrict__ lb1,
                                 const float* __restrict__ lw2, const float* __restrict__ lb2,
                                 const float* __restrict__ lw3, const float* __restrict__ lb3,
                                 float* __restrict__ le) {
    int e = blockIdx.x * 256 + threadIdx.x;
    if (e >= 4 * 33 * 33) return;
    int j = e % 33;
    int i = (e / 33) % 33;
    int b = e / (33 * 33);
    float d[3];
    #pragma unroll
    for (int c = 0; c < 3; ++c) {
        float a  = (i < 32) ? light[(b * 3 + c) * 32 + i] : -1.0f;
        float bb = (j < 32) ? light[(b * 3 + c) * 32 + j] : -1.0f;
        d[c] = a - bb;
    }
    float h1[8];
    #pragma unroll
    for (int o = 0; o < 8; ++o) {
        float s = lb1[o];
        #pragma unroll
        for (int c = 0; c < 3; ++c) s += lw1[o * 3 + c] * d[c];
        h1[o] = (s >= 0.f) ? s : 0.1f * s;
    }
    float h2[16];
    #pragma unroll
    for (int o = 0; o < 16; ++o) {
        float s = lb2[o];
        #pragma unroll
        for (int c = 0; c < 8; ++c) s += lw2[o * 8 + c] * h1[c];
        h2[o] = (s >= 0.f) ? s : 0.1f * s;
    }
    float* dst = le + (size_t)e * 32;
    #pragma unroll
    for (int o = 0; o < 32; ++o) {
        float s = lb3[o];
        #pragma unroll
        for (int c = 0; c < 16; ++c) s += lw3[o * 16 + c] * h2[c];
        dst[o] = s;
    }
}

// LDS pool offsets (bytes)
#define XS_OFF   0        // xs  [272 rows (n=px*33+m)][72] bf16   (whole kernel)
#define A1_OFF   39168    // wbuf [96][72] bf16 | scf f32 (px*1156+j'*36+i) | ob [256][40] bf16
#define KT_OFF   76160    // kT  [280 rows n][40] bf16  | abf [256][40] bf16
#define QT_OFF   98560    // qT  [264 rows n][40] bf16  | ao (px*2180+j'*68+oc) bf16
#define V2_OFF   119680   // v2  [(px*32+s)][40] bf16   | (ao spills here too)
#define WOL_OFF  140160   // wol [64][40] bf16
#define BIAS_OFF 145280   // f32[96]
#define BOL_OFF  145664   // f32[64]
#define POOL_SZ  145920

__launch_bounds__(TB, 1)
__global__ void fused_attn_kernel(const float* __restrict__ x,
                                  const float* __restrict__ wk, const float* __restrict__ bk,
                                  const float* __restrict__ wq, const float* __restrict__ bq,
                                  const float* __restrict__ wv, const float* __restrict__ bv,
                                  const float* __restrict__ wo, const float* __restrict__ bo,
                                  const float* __restrict__ le,
                                  float* __restrict__ out) {
    __shared__ __align__(16) unsigned char pool[POOL_SZ];
    uint16_t* xs   = (uint16_t*)(pool + XS_OFF);
    uint16_t* wbuf = (uint16_t*)(pool + A1_OFF);
    float*    scf  = (float*)   (pool + A1_OFF);
    uint16_t* ob   = (uint16_t*)(pool + A1_OFF);
    uint16_t* kT   = (uint16_t*)(pool + KT_OFF);
    uint16_t* abf  = (uint16_t*)(pool + KT_OFF);
    uint16_t* qT   = (uint16_t*)(pool + QT_OFF);
    uint16_t* ao   = (uint16_t*)(pool + QT_OFF);
    uint16_t* v2   = (uint16_t*)(pool + V2_OFF);
    uint16_t* wol  = (uint16_t*)(pool + WOL_OFF);
    float*    bias = (float*)   (pool + BIAS_OFF);
    float*    bol  = (float*)   (pool + BOL_OFF);

    const int t = threadIdx.x;
    // XCD swizzle: all 8 w-tiles of one (b,h) -> same XCD, co-resident
    const int i_  = blockIdx.x;
    const int w0  = ((i_ >> 3) & 7) << 3;
    const int bh  = ((i_ >> 6) << 3) | (i_ & 7);
    const int b   = bh >> 6;
    const int h   = bh & 63;

    const int lane = t & 63, wv_ = t >> 6;
    const int lrow = lane & 15;            // A-row / B-col / D-col selector
    const int lk   = (lane >> 4) << 3;     // k-group base (8 elems)
    const int drow = (lane >> 4) << 2;     // D-row base within tile

    // ---- P0: stage weights (bf16) + load x -> xs (bf16, transposed) ----
    for (int e = t; e < 96 * 64; e += TB) {
        int q = e >> 6, c = e & 63;
        float v = (q < 32) ? wk[e] : (q < 64) ? wq[e - 2048] : wv[e - 4096];
        wbuf[q * 72 + c] = f2bf(v);
    }
    if (t < 96) bias[t] = (t < 32) ? bk[t] : (t < 64) ? bq[t - 32] : bv[t - 64];
    for (int e = t; e < 61 * 32; e += TB) wol[(e >> 5) * 40 + (e & 31)] = f2bf(wo[e]);
    if (t < 64) bol[t] = (t < 61) ? bo[t] : 0.f;
    {
        const int fh = t & 1;
        #pragma unroll
        for (int it = 0; it < 8; ++it) {
            int p = (t >> 1) + it * 256;       // 0..2047 = (c,m)
            int c = p >> 5, m = p & 31;
            const float4 xv = *(const float4*)&x[(((size_t)(b * 64 + c) * 32 + m) * 64 + h) * 64 + w0 + fh * 4];
            int px0 = fh * 4;
            xs[((px0 + 0) * 33 + m + 1) * 72 + c] = f2bf(xv.x);
            xs[((px0 + 1) * 33 + m + 1) * 72 + c] = f2bf(xv.y);
            xs[((px0 + 2) * 33 + m + 1) * 72 + c] = f2bf(xv.z);
            xs[((px0 + 3) * 33 + m + 1) * 72 + c] = f2bf(xv.w);
        }
    }
    __syncthreads();

    // ---- A2: extra token row (m=0) = max over m=1..32 ----
    {
        const int c = t & 63, px = t >> 6;
        float mx = bf2f(xs[(px * 33 + 1) * 72 + c]);
        for (int m = 2; m <= 32; ++m) mx = fmaxf(mx, bf2f(xs[(px * 33 + m) * 72 + c]));
        xs[(px * 33) * 72 + c] = f2bf(mx);
    }
    __syncthreads();

    // ---- B: projections via MFMA: D[q][n] = W[q][c] * xs^T[c][n] + bias ----
    // M=96 (6 tiles), N=272 (17 tiles, n=px*33+m valid<264), K=64 (2 steps)
    for (int tt = wv_; tt < 102; tt += 8) {
        int mt = tt / 17, nt = tt - mt * 17;
        int arow = mt * 16 + lrow;
        int n = nt * 16 + lrow;
        short8 a0 = *(const short8*)&wbuf[arow * 72 + lk];
        short8 a1 = *(const short8*)&wbuf[arow * 72 + 32 + lk];
        short8 b0 = *(const short8*)&xs[n * 72 + lk];
        short8 b1 = *(const short8*)&xs[n * 72 + 32 + lk];
        int q0 = mt * 16 + drow;
        f32x4 acc = { bias[q0], bias[q0 + 1], bias[q0 + 2], bias[q0 + 3] };
        acc = MFMA(a0, b0, acc);
        acc = MFMA(a1, b1, acc);
        if (n < 264) {
            if (q0 < 32) {
                ushort4 pk = make_ushort4(f2bf(acc[0]), f2bf(acc[1]), f2bf(acc[2]), f2bf(acc[3]));
                *(ushort4*)&kT[n * 40 + q0] = pk;
            } else if (q0 < 64) {
                ushort4 pk = make_ushort4(f2bf(acc[0]), f2bf(acc[1]), f2bf(acc[2]), f2bf(acc[3]));
                *(ushort4*)&qT[n * 40 + (q0 - 32)] = pk;
            } else {
                int px = n / 33, m = n - px * 33;
                #pragma unroll
                for (int r = 0; r < 4; ++r)
                    v2[(px * 32 + (q0 - 64 + r)) * 40 + m] = f2bf(acc[r]);
            }
        }
    }
    __syncthreads();

    // ---- C1: scores via MFMA, per px: D[i][j'] = kT[i][s] * qT[j'+1][s]^T ----
    for (int tt = wv_; tt < 48; tt += 8) {
        int px = tt / 6, r = tt - px * 6;
        int mt = r >> 1, jh = r & 1;
        int ia = mt * 16 + lrow;
        int jp = jh * 16 + lrow;
        short8 af = *(const short8*)&kT[(px * 33 + ia) * 40 + lk];
        short8 bf = *(const short8*)&qT[(px * 33 + 1 + jp) * 40 + lk];
        f32x4 acc = { 0.f, 0.f, 0.f, 0.f };
        acc = MFMA(af, bf, acc);
        int i0 = mt * 16 + drow;
        float* dst = &scf[px * 1156 + jp * 36 + i0];
        if (mt < 2)           *(f32x4*)dst = acc;
        else if (drow == 0)   dst[0] = acc[0];   // only row i=32 valid in tile 2
    }
    __syncthreads();

    // ---- C2a: softmax over key index i per (px, j') column (scale folded) ----
    if (t < 256) {
        int px = t >> 5, jp = t & 31;
        float* col = &scf[px * 1156 + jp * 36];
        float mx = col[0];
        #pragma unroll 8
        for (int i = 1; i < 33; ++i) mx = fmaxf(mx, col[i]);
        float sum = 0.f;
        for (int i = 0; i < 33; ++i) { float e_ = __expf((col[i] - mx) * SCALE); sum += e_; col[i] = e_; }
        float r = 1.0f / sum;
        for (int i = 0; i < 33; ++i) col[i] *= r;
    }
    __syncthreads();

    // ---- C2b: a[i][j'] += sum_s q[s][i] * le[b][s][i][j'+1]  (VALU, b128 q reads) ----
    for (int e = t; e < 1056; e += TB) {
        int i = e % 33, jp = e / 33;
        const float* lep = le + ((size_t)(b * 1089 + i * 33 + (jp + 1))) * 32;
        float lev[32];
        #pragma unroll
        for (int s4 = 0; s4 < 8; ++s4) {
            float4 lv = *(const float4*)&lep[s4 * 4];
            lev[s4 * 4 + 0] = lv.x; lev[s4 * 4 + 1] = lv.y;
            lev[s4 * 4 + 2] = lv.z; lev[s4 * 4 + 3] = lv.w;
        }
        #pragma unroll
        for (int px = 0; px < 8; ++px) {
            const uint16_t* qp = &qT[(px * 33 + i) * 40];
            float acc = 0.f;
            #pragma unroll
            for (int g8 = 0; g8 < 4; ++g8) {
                short8 qv = *(const short8*)&qp[g8 * 8];
                #pragma unroll
                for (int k = 0; k < 8; ++k)
                    acc += bf2f((uint16_t)qv[k]) * lev[g8 * 8 + k];
            }
            scf[px * 1156 + jp * 36 + i] += acc;
        }
    }
    __syncthreads();

    // ---- convert: a (f32 scf) -> abf bf16 [n'=px*32+j'][i] stride 40 ----
    if (t < 256) {
        int px = t >> 5, jp = t & 31;
        const float* col = &scf[px * 1156 + jp * 36];
        uint16_t* dst = &abf[t * 40];
        #pragma unroll
        for (int i = 0; i < 33; ++i) dst[i] = f2bf(col[i]);
    }
    __syncthreads();

    // ---- C3: o via MFMA: D[s][n'] = v2[s][m] * abf[n'][m]^T  (+ m=32 tail) ----
    for (int tt = wv_; tt < 32; tt += 8) {
        int st = tt >> 4, nt = tt & 15, px = nt >> 1;
        int srow = st * 16 + lrow;
        int np = nt * 16 + lrow;
        short8 af = *(const short8*)&v2[(px * 32 + srow) * 40 + lk];
        short8 bf = *(const short8*)&abf[np * 40 + lk];
        f32x4 acc = { 0.f, 0.f, 0.f, 0.f };
        acc = MFMA(af, bf, acc);
        int s0 = st * 16 + drow;
        float a32 = bf2f(abf[np * 40 + 32]);
        #pragma unroll
        for (int r = 0; r < 4; ++r)
            acc[r] += bf2f(v2[(px * 32 + s0 + r) * 40 + 32]) * a32;
        ushort4 pk = make_ushort4(f2bf(acc[0]), f2bf(acc[1]), f2bf(acc[2]), f2bf(acc[3]));
        *(ushort4*)&ob[np * 40 + s0] = pk;   // ob[n'][s] stride 40
    }
    __syncthreads();

    // ---- D: ao via MFMA: D[oc][n'] = wol[oc][s] * ob[n'][s]^T + bo ----
    for (int tt = wv_; tt < 64; tt += 8) {
        int mt = tt >> 4, nt = tt & 15;
        int orow = mt * 16 + lrow;
        int np = nt * 16 + lrow;
        short8 af = *(const short8*)&wol[orow * 40 + lk];
        short8 bf = *(const short8*)&ob[np * 40 + lk];
        int oc0 = mt * 16 + drow;
        f32x4 acc = { bol[oc0], bol[oc0 + 1], bol[oc0 + 2], bol[oc0 + 3] };
        acc = MFMA(af, bf, acc);
        int px = np >> 5, jp = np & 31;
        ushort4 pk = make_ushort4(f2bf(acc[0]), f2bf(acc[1]), f2bf(acc[2]), f2bf(acc[3]));
        *(ushort4*)&ao[px * 2180 + jp * 68 + oc0] = pk;
    }
    __syncthreads();

    // ---- writer: out = xs (+ ao for c>=3), coalesced ----
    {
        const int px = t & 7, c = t >> 3;
        const size_t obase = (((size_t)(b * 64 + c)) * 32) * 4096 + (size_t)h * 64 + w0 + px;
        for (int m = 0; m < 32; ++m) {
            float v = bf2f(xs[(px * 33 + m + 1) * 72 + c]);
            if (c >= 3) v += bf2f(ao[px * 2180 + m * 68 + (c - 3)]);
            out[obase + (size_t)m * 4096] = v;
        }
    }
}

extern "C" void kernel_launch(void* const* d_in, const int* in_sizes, int n_in,
                              void* d_out, int out_size, void* d_ws, size_t ws_size,
                              hipStream_t stream) {
    const float* x     = (const float*)d_in[0];
    const float* light = (const float*)d_in[1];
    const float* wk  = (const float*)d_in[2];
    const float* bk  = (const float*)d_in[3];
    const float* wq  = (const float*)d_in[4];
    const float* bq  = (const float*)d_in[5];
    const float* wv  = (const float*)d_in[6];
    const float* bv  = (const float*)d_in[7];
    const float* wo  = (const float*)d_in[8];
    const float* bo  = (const float*)d_in[9];
    const float* lw1 = (const float*)d_in[10];
    const float* lb1 = (const float*)d_in[11];
    const float* lw2 = (const float*)d_in[12];
    const float* lb2 = (const float*)d_in[13];
    const float* lw3 = (const float*)d_in[14];
    const float* lb3 = (const float*)d_in[15];
    float* out = (float*)d_out;
    float* le  = (float*)d_ws;  // 4*33*33*32 f32 = 557 KB

    light_emb_kernel<<<dim3((4 * 33 * 33 + 255) / 256), dim3(256), 0, stream>>>(
        light, lw1, lb1, lw2, lb2, lw3, lb3, le);
    fused_attn_kernel<<<dim3(2048), dim3(TB), 0, stream>>>(
        x, wk, bk, wq, bq, wv, bv, wo, bo, le, out);
}

// Round 3
// 213.506 us; speedup vs baseline: 2.2762x; 1.0141x over previous
//
#include <hip/hip_runtime.h>
#include <stdint.h>

#define TB 512
#define SCALE 0.17677669529663687f  // 1/sqrt(32)

typedef __attribute__((ext_vector_type(8))) short short8;
typedef __attribute__((ext_vector_type(4))) float f32x4;
#define MFMA(a, b, c) __builtin_amdgcn_mfma_f32_16x16x32_bf16(a, b, c, 0, 0, 0)

__device__ __forceinline__ float bf2f(uint16_t u) {
    union { uint32_t i; float f; } v; v.i = ((uint32_t)u) << 16; return v.f;
}
__device__ __forceinline__ uint16_t f2bf(float f) {
    union { float f; uint32_t i; } v; v.f = f;
    uint32_t r = v.i + 0x7fffu + ((v.i >> 16) & 1u);
    return (uint16_t)(r >> 16);
}
// xs element index: row n (0..131), channel c (0..63); XOR-swizzle 8-elem chunks
__device__ __forceinline__ int swz(int n, int c) {
    return (n << 6) + (c ^ ((n & 7) << 3));
}

// ---------------- K1: light positional embedding -> le[b][i][j][s] (f32) ----------------
__global__ void light_emb_kernel(const float* __restrict__ light,
                                 const float* __restrict__ lw1, const float* __restrict__ lb1,
                                 const float* __restrict__ lw2, const float* __restrict__ lb2,
                                 const float* __restrict__ lw3, const float* __restrict__ lb3,
                                 float* __restrict__ le) {
    int e = blockIdx.x * 256 + threadIdx.x;
    if (e >= 4 * 33 * 33) return;
    int j = e % 33;
    int i = (e / 33) % 33;
    int b = e / (33 * 33);
    float d[3];
    #pragma unroll
    for (int c = 0; c < 3; ++c) {
        float a  = (i < 32) ? light[(b * 3 + c) * 32 + i] : -1.0f;
        float bb = (j < 32) ? light[(b * 3 + c) * 32 + j] : -1.0f;
        d[c] = a - bb;
    }
    float h1[8];
    #pragma unroll
    for (int o = 0; o < 8; ++o) {
        float s = lb1[o];
        #pragma unroll
        for (int c = 0; c < 3; ++c) s += lw1[o * 3 + c] * d[c];
        h1[o] = (s >= 0.f) ? s : 0.1f * s;
    }
    float h2[16];
    #pragma unroll
    for (int o = 0; o < 16; ++o) {
        float s = lb2[o];
        #pragma unroll
        for (int c = 0; c < 8; ++c) s += lw2[o * 8 + c] * h1[c];
        h2[o] = (s >= 0.f) ? s : 0.1f * s;
    }
    float* dst = le + (size_t)e * 32;
    #pragma unroll
    for (int o = 0; o < 32; ++o) {
        float s = lb3[o];
        #pragma unroll
        for (int c = 0; c < 16; ++c) s += lw3[o * 16 + c] * h2[c];
        dst[o] = s;
    }
}

// LDS pool offsets (bytes), PX=4, total 70912 B -> 2 blocks/CU
#define XS_OFF   0        // xs  [132 n][64 c] bf16, chunk-XOR swizzled        = 16896
#define R1_OFF   16896    // wbuf [96][72] bf16 =13824 | scf f32 px*1056+jp*33+i =16896 | ob [128][40] bf16 =10240
#define R2_OFF   33792    // kT  [132][40] bf16 =10560 | abf [128][40] bf16 =10240
#define R3_OFF   44352    // qT  [132][40] bf16 =10560 | ao (px*2180+m*68+oc) bf16 =17440 (spans into R4)
#define R4_OFF   54912    // v2  [128][40] bf16 =10240
#define R5_OFF   65152    // wol [64][40] bf16 =5120
#define BIAS_OFF 70272    // f32[96]
#define BOL_OFF  70656    // f32[64]
#define POOL_SZ  70912

__global__ void __launch_bounds__(TB, 4)
fused_attn_kernel(const float* __restrict__ x,
                  const float* __restrict__ wk, const float* __restrict__ bk,
                  const float* __restrict__ wq, const float* __restrict__ bq,
                  const float* __restrict__ wv, const float* __restrict__ bv,
                  const float* __restrict__ wo, const float* __restrict__ bo,
                  const float* __restrict__ le,
                  float* __restrict__ out) {
    __shared__ __align__(16) unsigned char pool[POOL_SZ];
    uint16_t* xs   = (uint16_t*)(pool + XS_OFF);
    uint16_t* wbuf = (uint16_t*)(pool + R1_OFF);
    float*    scf  = (float*)   (pool + R1_OFF);
    uint16_t* ob   = (uint16_t*)(pool + R1_OFF);
    uint16_t* kT   = (uint16_t*)(pool + R2_OFF);
    uint16_t* abf  = (uint16_t*)(pool + R2_OFF);
    uint16_t* qT   = (uint16_t*)(pool + R3_OFF);
    uint16_t* ao   = (uint16_t*)(pool + R3_OFF);
    uint16_t* v2   = (uint16_t*)(pool + R4_OFF);
    uint16_t* wol  = (uint16_t*)(pool + R5_OFF);
    float*    bias = (float*)   (pool + BIAS_OFF);
    float*    bol  = (float*)   (pool + BOL_OFF);

    const int t = threadIdx.x;
    // XCD swizzle: all 16 w-tiles of one (b,h) on the same XCD, adjacent dispatch
    const int i_  = blockIdx.x;
    const int w0  = ((i_ >> 3) & 15) << 2;
    const int bh  = ((i_ >> 7) << 3) | (i_ & 7);
    const int b   = bh >> 6;
    const int h   = bh & 63;

    const int lane = t & 63, wv_ = t >> 6;
    const int lrow = lane & 15;            // A-row / B-col / D-col selector
    const int lk   = (lane >> 4) << 3;     // k-chunk base (8 elems)
    const int drow = (lane >> 4) << 2;     // D-row base within tile

    // ---- P0: stage weights (bf16) + load x -> xs (bf16, swizzled) ----
    for (int e = t; e < 96 * 64; e += TB) {
        int q = e >> 6, c = e & 63;
        float v = (q < 32) ? wk[e] : (q < 64) ? wq[e - 2048] : wv[e - 4096];
        wbuf[q * 72 + c] = f2bf(v);
    }
    if (t < 96) bias[t] = (t < 32) ? bk[t] : (t < 64) ? bq[t - 32] : bv[t - 64];
    for (int e = t; e < 64 * 32; e += TB) {
        int oc = e >> 5, s = e & 31;
        wol[oc * 40 + s] = (oc < 61) ? f2bf(wo[oc * 32 + s]) : (uint16_t)0;
    }
    if (t < 64) bol[t] = (t < 61) ? bo[t] : 0.f;
    {
        const int m = t & 31, cg = t >> 5;       // cg 0..15, c0 = cg*4
        const int c0 = cg * 4;
        float4 xv[4];
        #pragma unroll
        for (int i = 0; i < 4; ++i)
            xv[i] = *(const float4*)&x[(((size_t)(b * 64 + c0 + i) * 32 + m) * 64 + h) * 64 + w0];
        #pragma unroll
        for (int px = 0; px < 4; ++px) {
            int n = px * 33 + m + 1;
            ushort4 pk = make_ushort4(f2bf(((const float*)&xv[0])[px]),
                                      f2bf(((const float*)&xv[1])[px]),
                                      f2bf(((const float*)&xv[2])[px]),
                                      f2bf(((const float*)&xv[3])[px]));
            *(ushort4*)&xs[swz(n, c0)] = pk;
        }
    }
    __syncthreads();

    // ---- A2: extra token row (n = px*33) = max over m=1..32 ----
    if (t < 256) {
        const int c = t & 63, px = t >> 6;
        float mx = bf2f(xs[swz(px * 33 + 1, c)]);
        for (int m = 2; m <= 32; ++m) mx = fmaxf(mx, bf2f(xs[swz(px * 33 + m, c)]));
        xs[swz(px * 33, c)] = f2bf(mx);
    }
    __syncthreads();

    // ---- B: projections via MFMA: D[q][n] = W[q][c] * xs^T[c][n] + bias ----
    // M=96 (6 mt), N=132 (9 nt), K=64 (2 MFMA)
    for (int tt = wv_; tt < 54; tt += 8) {
        int mt = tt / 9, nt = tt - mt * 9;
        int arow = mt * 16 + lrow;
        int n = nt * 16 + lrow;
        short8 a0 = *(const short8*)&wbuf[arow * 72 + lk];
        short8 a1 = *(const short8*)&wbuf[arow * 72 + 32 + lk];
        short8 b0 = *(const short8*)&xs[swz(n, lk)];
        short8 b1 = *(const short8*)&xs[swz(n, 32 + lk)];
        int q0 = mt * 16 + drow;
        f32x4 acc = { bias[q0], bias[q0 + 1], bias[q0 + 2], bias[q0 + 3] };
        acc = MFMA(a0, b0, acc);
        acc = MFMA(a1, b1, acc);
        if (n < 132) {
            if (q0 < 32) {
                ushort4 pk = make_ushort4(f2bf(acc[0]), f2bf(acc[1]), f2bf(acc[2]), f2bf(acc[3]));
                *(ushort4*)&kT[n * 40 + q0] = pk;
            } else if (q0 < 64) {
                ushort4 pk = make_ushort4(f2bf(acc[0]), f2bf(acc[1]), f2bf(acc[2]), f2bf(acc[3]));
                *(ushort4*)&qT[n * 40 + (q0 - 32)] = pk;
            } else {
                int px = n / 33, m = n - px * 33;
                #pragma unroll
                for (int r = 0; r < 4; ++r)
                    v2[(px * 32 + (q0 - 64 + r)) * 40 + m] = f2bf(acc[r]);
            }
        }
    }
    __syncthreads();

    // ---- C1: scores via MFMA, per px: D[i][j'] = kT[i][s] * qT[j'+1][s]^T ----
    for (int tt = wv_; tt < 24; tt += 8) {
        int px = tt / 6, r = tt - px * 6;
        int mt = r >> 1, jh = r & 1;
        int ia = mt * 16 + lrow;
        int jp = jh * 16 + lrow;
        short8 af = *(const short8*)&kT[(px * 33 + ia) * 40 + lk];
        short8 bf = *(const short8*)&qT[(px * 33 + 1 + jp) * 40 + lk];
        f32x4 acc = { 0.f, 0.f, 0.f, 0.f };
        acc = MFMA(af, bf, acc);
        int i0 = mt * 16 + drow;
        float* dst = &scf[px * 1056 + jp * 33];
        if (mt < 2) {
            #pragma unroll
            for (int r2 = 0; r2 < 4; ++r2) dst[i0 + r2] = acc[r2];
        } else if (drow == 0) {
            dst[32] = acc[0];      // only i=32 valid in tile mt=2
        }
    }
    __syncthreads();

    // ---- C2a: softmax over key index i per (px, j') column (scale folded) ----
    if (t < 128) {
        int px = t >> 5, jp = t & 31;
        float* col = &scf[px * 1056 + jp * 33];
        float mx = col[0];
        #pragma unroll 8
        for (int i = 1; i < 33; ++i) mx = fmaxf(mx, col[i]);
        float sum = 0.f;
        for (int i = 0; i < 33; ++i) { float e_ = __expf((col[i] - mx) * SCALE); sum += e_; col[i] = e_; }
        float r = 1.0f / sum;
        for (int i = 0; i < 33; ++i) col[i] *= r;
    }
    __syncthreads();

    // ---- C2b: a[i][j'] = softmax + sum_s q[s][i]*le[b][s][i][j'+1]; write bf16 abf ----
    for (int e = t; e < 1056; e += TB) {
        int i = e % 33, jp = e / 33;
        const float* lep = le + ((size_t)(b * 1089 + i * 33 + (jp + 1))) * 32;
        float lev[32];
        #pragma unroll
        for (int s4 = 0; s4 < 8; ++s4) {
            float4 lv = *(const float4*)&lep[s4 * 4];
            lev[s4 * 4 + 0] = lv.x; lev[s4 * 4 + 1] = lv.y;
            lev[s4 * 4 + 2] = lv.z; lev[s4 * 4 + 3] = lv.w;
        }
        #pragma unroll
        for (int px = 0; px < 4; ++px) {
            const uint16_t* qp = &qT[(px * 33 + i) * 40];
            float acc = 0.f;
            #pragma unroll
            for (int g8 = 0; g8 < 4; ++g8) {
                short8 qv = *(const short8*)&qp[g8 * 8];
                #pragma unroll
                for (int k = 0; k < 8; ++k)
                    acc += bf2f((uint16_t)qv[k]) * lev[g8 * 8 + k];
            }
            float fin = scf[px * 1056 + jp * 33 + i] + acc;
            abf[(px * 32 + jp) * 40 + i] = f2bf(fin);
        }
    }
    __syncthreads();

    // ---- C3: o via MFMA: D[s][n'] = v2[s][m] * abf[n'][m]^T  (+ m=32 tail) ----
    for (int tt = wv_; tt < 16; tt += 8) {
        int st = tt >> 3, nt = tt & 7, px = nt >> 1;
        int srow = st * 16 + lrow;
        int np = nt * 16 + lrow;
        short8 af = *(const short8*)&v2[(px * 32 + srow) * 40 + lk];
        short8 bf = *(const short8*)&abf[np * 40 + lk];
        f32x4 acc = { 0.f, 0.f, 0.f, 0.f };
        acc = MFMA(af, bf, acc);
        int s0 = st * 16 + drow;
        float a32 = bf2f(abf[np * 40 + 32]);
        #pragma unroll
        for (int r = 0; r < 4; ++r)
            acc[r] += bf2f(v2[(px * 32 + s0 + r) * 40 + 32]) * a32;
        ushort4 pk = make_ushort4(f2bf(acc[0]), f2bf(acc[1]), f2bf(acc[2]), f2bf(acc[3]));
        *(ushort4*)&ob[np * 40 + s0] = pk;   // ob[n'][s] stride 40
    }
    __syncthreads();

    // ---- D: ao via MFMA: D[oc][n'] = wol[oc][s] * ob[n'][s]^T + bo ----
    for (int tt = wv_; tt < 32; tt += 8) {
        int mt = tt >> 3, nt = tt & 7;
        int orow = mt * 16 + lrow;
        int np = nt * 16 + lrow;
        short8 af = *(const short8*)&wol[orow * 40 + lk];
        short8 bf = *(const short8*)&ob[np * 40 + lk];
        int oc0 = mt * 16 + drow;
        f32x4 acc = { bol[oc0], bol[oc0 + 1], bol[oc0 + 2], bol[oc0 + 3] };
        acc = MFMA(af, bf, acc);
        int px = np >> 5, jp = np & 31;
        ushort4 pk = make_ushort4(f2bf(acc[0]), f2bf(acc[1]), f2bf(acc[2]), f2bf(acc[3]));
        *(ushort4*)&ao[px * 2180 + jp * 68 + oc0] = pk;
    }
    __syncthreads();

    // ---- writer: out = xs (+ ao for c>=3), 16B-segment coalesced stores ----
    {
        const int px = t & 3, m = (t >> 2) & 31, cq = t >> 7;  // cq 0..3
        const int n = px * 33 + m + 1;
        short8 xv0 = *(const short8*)&xs[swz(n, cq * 16)];
        short8 xv1 = *(const short8*)&xs[swz(n, cq * 16 + 8)];
        const size_t obase = (((size_t)(b * 64 + cq * 16) * 32 + m)) * 4096 + (size_t)h * 64 + w0 + px;
        #pragma unroll
        for (int k = 0; k < 16; ++k) {
            int c = cq * 16 + k;
            float v = bf2f((uint16_t)(k < 8 ? xv0[k] : xv1[k - 8]));
            if (c >= 3) v += bf2f(ao[px * 2180 + m * 68 + (c - 3)]);
            out[obase + (size_t)k * (32 * 4096)] = v;
        }
    }
}

extern "C" void kernel_launch(void* const* d_in, const int* in_sizes, int n_in,
                              void* d_out, int out_size, void* d_ws, size_t ws_size,
                              hipStream_t stream) {
    const float* x     = (const float*)d_in[0];
    const float* light = (const float*)d_in[1];
    const float* wk  = (const float*)d_in[2];
    const float* bk  = (const float*)d_in[3];
    const float* wq  = (const float*)d_in[4];
    const float* bq  = (const float*)d_in[5];
    const float* wv  = (const float*)d_in[6];
    const float* bv  = (const float*)d_in[7];
    const float* wo  = (const float*)d_in[8];
    const float* bo  = (const float*)d_in[9];
    const float* lw1 = (const float*)d_in[10];
    const float* lb1 = (const float*)d_in[11];
    const float* lw2 = (const float*)d_in[12];
    const float* lb2 = (const float*)d_in[13];
    const float* lw3 = (const float*)d_in[14];
    const float* lb3 = (const float*)d_in[15];
    float* out = (float*)d_out;
    float* le  = (float*)d_ws;  // 4*33*33*32 f32 = 557 KB

    light_emb_kernel<<<dim3((4 * 33 * 33 + 255) / 256), dim3(256), 0, stream>>>(
        light, lw1, lb1, lw2, lb2, lw3, lb3, le);
    fused_attn_kernel<<<dim3(4096), dim3(TB), 0, stream>>>(
        x, wk, bk, wq, bq, wv, bv, wo, bo, le, out);
}